// Round 1
// 2576.870 us; speedup vs baseline: 1.1498x; 1.1498x over previous
//
#include <hip/hip_runtime.h>

#define TT 2048
#define BQ 512
#define LAYERS 10
#define NC 7
#define CH 8               // timesteps per chunk (per barrier interval)
#define NCH (TT / CH)      // 256 chunks

typedef _Float16 half2v __attribute__((ext_vector_type(2)));

__device__ __forceinline__ float sigm(float z) {
  return __builtin_amdgcn_rcpf(1.0f + __expf(-z));
}
// f32 += dot(f16x2, f16x2) -- v_dot2_f32_f16
__device__ __forceinline__ float dot2(unsigned w, unsigned v, float acc) {
  return __builtin_amdgcn_fdot2(__builtin_bit_cast(half2v, w),
                                __builtin_bit_cast(half2v, v), acc, false);
}
// RNE pack of two floats into f16x2 dword
__device__ __forceinline__ unsigned pkh2(float a, float b) {
  union { _Float16 h[2]; unsigned u; } z;
  z.h[0] = (_Float16)a; z.h[1] = (_Float16)b;
  return z.u;
}

// R9: chunked systolic pipeline -- CH=8 timesteps per barrier interval.
// R8 post-mortem: VALUBusy 56%, HBM 0.7%, bank-conflict 0 -> the 2058
// per-step __syncthreads() lockstep was the stall source, not any pipe.
// Waves need adjacent-wave handoff only once per CHUNK: wave w processes
// chunk mc=m-w (8 cells) per step; h chunks live in double-buffered LDS
// slots (parity = step&1). Within a chunk the wave's own h recurrence is
// same-wave LDS write->read (lgkmcnt-ordered, no barrier). Barriers:
// 2058 -> 266. Cell math is bit-identical to R8.
//   slot 0      = x chunk (wave 0 self-stages one chunk ahead)
//   slot w+1    = h_w chunk (published cell-by-cell; next wave reads the
//                 other parity next step; own j=0 readback uses prev
//                 parity cell CH-1)
// FC wave: 56 lanes = 8 timesteps x 7 classes per step (was 7 lanes/step).
__launch_bounds__(704)
__global__ void lstm_fused(const float* __restrict__ x,
                           const float* __restrict__ h0,
                           const float* __restrict__ c0,
                           const float* __restrict__ Wih,
                           const float* __restrict__ Whh,
                           const float* __restrict__ bias,
                           const float* __restrict__ fcw,
                           const float* __restrict__ fcb,
                           float* __restrict__ out) {
  // hs[parity][slot][cell][dword]: 13 f16x2 dwords used, stride 16 (64B)
  __shared__ __align__(16) unsigned hs[2][LAYERS + 1][CH][16];
  __shared__ float eb[CH][8];   // FC softmax exp staging

  const int tid = threadIdx.x;
  const int w = tid >> 6;          // wave: 0..9 layers, 10 = FC
  const int lane = tid & 63;
  const int b = blockIdx.x;        // batch element
  const int g = lane & 1;
  const int u = lane >> 1;
  const bool on = (w < LAYERS) && (lane < 50);
  const bool isfc = (w == LAYERS) && (lane < 7 * CH);
  const int jg = lane / 7;                 // FC: cell within chunk
  const int cls = lane - jg * 7;           // FC: class

  unsigned wi1p[13], wi2p[13], wh1p[13], wh2p[13];  // f16-pair weights
  float b1 = 0.f, b2 = 0.f, c = 0.f;
  float xa = 0.f, xb = 0.f;        // wave-0 x stage regs (next t)
  int tstage = TT;                 // next t to load (TT = inactive)
  const float* xnext = x;

  if (on) {
    const int r1 = g ? (u + 25) : u;        // f_u : i_u
    const int r2 = g ? (u + 75) : (u + 50); // o_u : g_u
    const float* pi1 = Wih + (w * 100 + r1) * 25;
    const float* pi2 = Wih + (w * 100 + r2) * 25;
    const float* ph1 = Whh + (w * 100 + r1) * 25;
    const float* ph2 = Whh + (w * 100 + r2) * 25;
#pragma unroll
    for (int j = 0; j < 13; ++j) {
      const int k0 = 2 * j, k1 = 2 * j + 1;
      const float e1 = (k1 < 25) ? pi1[k1] : 0.f;
      const float e2 = (k1 < 25) ? pi2[k1] : 0.f;
      const float e3 = (k1 < 25) ? ph1[k1] : 0.f;
      const float e4 = (k1 < 25) ? ph2[k1] : 0.f;
      wi1p[j] = pkh2(pi1[k0], e1);
      wi2p[j] = pkh2(pi2[k0], e2);
      wh1p[j] = pkh2(ph1[k0], e3);
      wh2p[j] = pkh2(ph2[k0], e4);
    }
    b1 = bias[w * 100 + r1];
    b2 = bias[w * 100 + r2];
    if (g == 0) c = c0[(w * BQ + b) * 25 + u];
  } else if (isfc) {
    const float* pf = fcw + cls * 25;
#pragma unroll
    for (int j = 0; j < 13; ++j) {
      const int k0 = 2 * j, k1 = 2 * j + 1;
      wh1p[j] = pkh2(pf[k0], (k1 < 25) ? pf[k1] : 0.f);
    }
    b1 = fcb[cls];
  }

  // h0 -> packed pairs at [prev-parity of first active step][w+1][CH-1].
  // First active step is m=w, read parity (w&1)^1.
  {
    float h00 = 0.f;
    if (on && g == 0) h00 = h0[(w * BQ + b) * 25 + u];
    const float hp = __shfl_xor(h00, 2);       // partner owner (u^1)
    if (on && (lane & 3) == 0) {
      hs[(w & 1) ^ 1][w + 1][CH - 1][lane >> 2] =
          pkh2(h00, (u == 24) ? 0.f : hp);
    }
  }
  // x chunk 0 -> parity 1 (read at m=0); prefetch regs for t=CH.
  if (w == 0 && lane < 13) {
#pragma unroll
    for (int j = 0; j < CH; ++j) {
      const float* p = x + ((size_t)j * BQ + b) * 25;
      const float a0 = p[2 * lane];
      const float b0 = (lane < 12) ? p[2 * lane + 1] : 0.f;
      hs[1][0][j][lane] = pkh2(a0, b0);
    }
    const float* p = x + ((size_t)CH * BQ + b) * 25;
    xa = p[2 * lane];
    xb = (lane < 12) ? p[2 * lane + 1] : 0.f;
    tstage = CH;
    xnext = x + ((size_t)(CH + 1) * BQ + b) * 25;
  }
  __syncthreads();

  const float s2 = g ? 1.0f : 2.0f;            // gate2: tanh (g) vs sigm (o)
  const float s2m1 = s2 - 1.0f;

  for (int m = 0; m < NCH + LAYERS; ++m) {
    const int pr = (m & 1) ^ 1;                // read parity
    const int pw = m & 1;                      // write parity

    if (w < LAYERS) {
      const int mc = m - w;                    // chunk index (wave-uniform)
      if ((unsigned)mc < (unsigned)NCH) {
        const unsigned* ib = &hs[pr][w][0][0];          // input chunk
        const unsigned* o0 = &hs[pr][w + 1][CH - 1][0]; // own h(mc*CH-1)
        unsigned* ob = &hs[pw][w + 1][0][0];            // own publish chunk
        unsigned* xst = &hs[pw][0][0][0];               // wave-0 stage chunk

#pragma unroll
        for (int j = 0; j < CH; ++j) {
          // wave-0: stage x(t) for chunk m+1 (regs loaded one cell ago)
          if (w == 0 && lane < 13 && tstage < TT) {
            xst[j * 16 + lane] = pkh2(xa, xb);
            ++tstage;
            if (tstage < TT) {
              xa = xnext[2 * lane];
              xb = (lane < 12) ? xnext[2 * lane + 1] : 0.f;
              xnext += (size_t)BQ * 25;
            }
          }
          if (lane < 50) {
            const unsigned* ip = ib + j * 16;
            const unsigned* op = (j == 0) ? o0 : (ob + (j - 1) * 16);
            const uint4 I0 = *(const uint4*)(ip + 0);
            const uint4 I1 = *(const uint4*)(ip + 4);
            const uint4 I2 = *(const uint4*)(ip + 8);
            const unsigned I3 = ip[12];
            const uint4 O0 = *(const uint4*)(op + 0);
            const uint4 O1 = *(const uint4*)(op + 4);
            const uint4 O2 = *(const uint4*)(op + 8);
            const unsigned O3 = op[12];

            float a1 = b1, a2 = b2, h1 = 0.f, h2 = 0.f;
            a1 = dot2(wi1p[0],  I0.x, a1);  a2 = dot2(wi2p[0],  I0.x, a2);
            a1 = dot2(wi1p[1],  I0.y, a1);  a2 = dot2(wi2p[1],  I0.y, a2);
            a1 = dot2(wi1p[2],  I0.z, a1);  a2 = dot2(wi2p[2],  I0.z, a2);
            a1 = dot2(wi1p[3],  I0.w, a1);  a2 = dot2(wi2p[3],  I0.w, a2);
            a1 = dot2(wi1p[4],  I1.x, a1);  a2 = dot2(wi2p[4],  I1.x, a2);
            a1 = dot2(wi1p[5],  I1.y, a1);  a2 = dot2(wi2p[5],  I1.y, a2);
            a1 = dot2(wi1p[6],  I1.z, a1);  a2 = dot2(wi2p[6],  I1.z, a2);
            a1 = dot2(wi1p[7],  I1.w, a1);  a2 = dot2(wi2p[7],  I1.w, a2);
            a1 = dot2(wi1p[8],  I2.x, a1);  a2 = dot2(wi2p[8],  I2.x, a2);
            a1 = dot2(wi1p[9],  I2.y, a1);  a2 = dot2(wi2p[9],  I2.y, a2);
            a1 = dot2(wi1p[10], I2.z, a1);  a2 = dot2(wi2p[10], I2.z, a2);
            a1 = dot2(wi1p[11], I2.w, a1);  a2 = dot2(wi2p[11], I2.w, a2);
            a1 = dot2(wi1p[12], I3,   a1);  a2 = dot2(wi2p[12], I3,   a2);
            h1 = dot2(wh1p[0],  O0.x, h1);  h2 = dot2(wh2p[0],  O0.x, h2);
            h1 = dot2(wh1p[1],  O0.y, h1);  h2 = dot2(wh2p[1],  O0.y, h2);
            h1 = dot2(wh1p[2],  O0.z, h1);  h2 = dot2(wh2p[2],  O0.z, h2);
            h1 = dot2(wh1p[3],  O0.w, h1);  h2 = dot2(wh2p[3],  O0.w, h2);
            h1 = dot2(wh1p[4],  O1.x, h1);  h2 = dot2(wh2p[4],  O1.x, h2);
            h1 = dot2(wh1p[5],  O1.y, h1);  h2 = dot2(wh2p[5],  O1.y, h2);
            h1 = dot2(wh1p[6],  O1.z, h1);  h2 = dot2(wh2p[6],  O1.z, h2);
            h1 = dot2(wh1p[7],  O1.w, h1);  h2 = dot2(wh2p[7],  O1.w, h2);
            h1 = dot2(wh1p[8],  O2.x, h1);  h2 = dot2(wh2p[8],  O2.x, h2);
            h1 = dot2(wh1p[9],  O2.y, h1);  h2 = dot2(wh2p[9],  O2.y, h2);
            h1 = dot2(wh1p[10], O2.z, h1);  h2 = dot2(wh2p[10], O2.z, h2);
            h1 = dot2(wh1p[11], O2.w, h1);  h2 = dot2(wh2p[11], O2.w, h2);
            h1 = dot2(wh1p[12], O3,   h1);  h2 = dot2(wh2p[12], O3,   h2);

            const float p1 = a1 + h1;
            const float p2 = a2 + h2;
            const float G1 = sigm(p1);                    // i (g=0) / f (g=1)
            const float G2 = s2 * sigm(s2 * p2) - s2m1;   // tanh g / sigm o

            const float q1 = __shfl_xor(G1, 1);           // partner's pair
            const float q2 = __shfl_xor(G2, 1);

            if (g == 0) {                                 // q1=f, q2=o
              c = q1 * c + G1 * G2;                       // f*c + i*g
              const float th = 2.0f * sigm(2.0f * c) - 1.0f;
              const float h = q2 * th;                    // o * tanh(c)
              const float hp = __shfl_xor(h, 2);          // partner owner's h
              if ((lane & 3) == 0) {                      // even-u owners
                ob[j * 16 + (lane >> 2)] =
                    pkh2(h, (u == 24) ? 0.f : hp);
              }
            } else {
              __shfl_xor(0.f, 2);  // keep shfl lane-pairing well-defined
            }
          }
        }
      }
    } else if (isfc) {
      // FC + softmax: chunk mc = m-10 (written by wave 9 at step m-1,
      // parity pr). 56 lanes = 8 cells x 7 classes.
      const int mc = m - LAYERS;
      if ((unsigned)mc < (unsigned)NCH) {
        const unsigned* hp = &hs[pr][LAYERS][jg][0];
        const uint4 H0 = *(const uint4*)(hp + 0);
        const uint4 H1 = *(const uint4*)(hp + 4);
        const uint4 H2 = *(const uint4*)(hp + 8);
        const unsigned H3 = hp[12];
        float acc = b1;
        acc = dot2(wh1p[0],  H0.x, acc);
        acc = dot2(wh1p[1],  H0.y, acc);
        acc = dot2(wh1p[2],  H0.z, acc);
        acc = dot2(wh1p[3],  H0.w, acc);
        acc = dot2(wh1p[4],  H1.x, acc);
        acc = dot2(wh1p[5],  H1.y, acc);
        acc = dot2(wh1p[6],  H1.z, acc);
        acc = dot2(wh1p[7],  H1.w, acc);
        acc = dot2(wh1p[8],  H2.x, acc);
        acc = dot2(wh1p[9],  H2.y, acc);
        acc = dot2(wh1p[10], H2.z, acc);
        acc = dot2(wh1p[11], H2.w, acc);
        acc = dot2(wh1p[12], H3,   acc);
        const float e = __expf(acc);            // logits small; no max-sub
        eb[jg][cls] = e;                        // same-wave LDS, ordered
        const float ssum = eb[jg][0] + eb[jg][1] + eb[jg][2] + eb[jg][3] +
                           eb[jg][4] + eb[jg][5] + eb[jg][6];
        const int t = mc * CH + jg;
        out[((size_t)t * BQ + b) * NC + cls] =
            e * __builtin_amdgcn_rcpf(ssum);
      }
    }
    __syncthreads();   // ONE barrier per chunk-step (266 total)
  }
}

extern "C" void kernel_launch(void* const* d_in, const int* in_sizes, int n_in,
                              void* d_out, int out_size, void* d_ws, size_t ws_size,
                              hipStream_t stream) {
  const float* x   = (const float*)d_in[0];
  const float* h0  = (const float*)d_in[1];
  const float* c0  = (const float*)d_in[2];
  const float* Wih = (const float*)d_in[3];
  const float* Whh = (const float*)d_in[4];
  const float* b   = (const float*)d_in[5];
  const float* fcw = (const float*)d_in[6];
  const float* fcb = (const float*)d_in[7];
  float* out = (float*)d_out;

  lstm_fused<<<dim3(512), dim3(704), 0, stream>>>(x, h0, c0, Wih, Whh, b, fcw,
                                                  fcb, out);
}

// Round 2
// 2403.797 us; speedup vs baseline: 1.2326x; 1.0720x over previous
//
#include <hip/hip_runtime.h>

#define TT 2048
#define BQ 512
#define LAYERS 10
#define NC 7
#define CH 8               // timesteps per chunk (per barrier interval)
#define NCH (TT / CH)      // 256 chunks

typedef _Float16 half2v __attribute__((ext_vector_type(2)));

__device__ __forceinline__ float sigm(float z) {
  return __builtin_amdgcn_rcpf(1.0f + __expf(-z));
}
// f32 += dot(f16x2, f16x2) -- v_dot2_f32_f16
__device__ __forceinline__ float dot2(unsigned w, unsigned v, float acc) {
  return __builtin_amdgcn_fdot2(__builtin_bit_cast(half2v, w),
                                __builtin_bit_cast(half2v, v), acc, false);
}
// RNE pack of two floats into f16x2 dword
__device__ __forceinline__ unsigned pkh2(float a, float b) {
  union { _Float16 h[2]; unsigned u; } z;
  z.h[0] = (_Float16)a; z.h[1] = (_Float16)b;
  return z.u;
}

// One LSTM cell for one batch element (bit-identical math to R9).
// ip: input slot (x or h_{w-1}), op: own-h slot, dst: publish slot.
__device__ __forceinline__ void lstm_cell(
    const unsigned* __restrict__ ip, const unsigned* __restrict__ op,
    const unsigned* wi1p, const unsigned* wi2p,
    const unsigned* wh1p, const unsigned* wh2p,
    float b1, float b2, float s2, float s2m1,
    int g, int u, int lane, float& c, unsigned* __restrict__ dst) {
  const uint4 I0 = *(const uint4*)(ip + 0);
  const uint4 I1 = *(const uint4*)(ip + 4);
  const uint4 I2 = *(const uint4*)(ip + 8);
  const unsigned I3 = ip[12];
  const uint4 O0 = *(const uint4*)(op + 0);
  const uint4 O1 = *(const uint4*)(op + 4);
  const uint4 O2 = *(const uint4*)(op + 8);
  const unsigned O3 = op[12];

  float a1 = b1, a2 = b2, h1 = 0.f, h2 = 0.f;
  a1 = dot2(wi1p[0],  I0.x, a1);  a2 = dot2(wi2p[0],  I0.x, a2);
  a1 = dot2(wi1p[1],  I0.y, a1);  a2 = dot2(wi2p[1],  I0.y, a2);
  a1 = dot2(wi1p[2],  I0.z, a1);  a2 = dot2(wi2p[2],  I0.z, a2);
  a1 = dot2(wi1p[3],  I0.w, a1);  a2 = dot2(wi2p[3],  I0.w, a2);
  a1 = dot2(wi1p[4],  I1.x, a1);  a2 = dot2(wi2p[4],  I1.x, a2);
  a1 = dot2(wi1p[5],  I1.y, a1);  a2 = dot2(wi2p[5],  I1.y, a2);
  a1 = dot2(wi1p[6],  I1.z, a1);  a2 = dot2(wi2p[6],  I1.z, a2);
  a1 = dot2(wi1p[7],  I1.w, a1);  a2 = dot2(wi2p[7],  I1.w, a2);
  a1 = dot2(wi1p[8],  I2.x, a1);  a2 = dot2(wi2p[8],  I2.x, a2);
  a1 = dot2(wi1p[9],  I2.y, a1);  a2 = dot2(wi2p[9],  I2.y, a2);
  a1 = dot2(wi1p[10], I2.z, a1);  a2 = dot2(wi2p[10], I2.z, a2);
  a1 = dot2(wi1p[11], I2.w, a1);  a2 = dot2(wi2p[11], I2.w, a2);
  a1 = dot2(wi1p[12], I3,   a1);  a2 = dot2(wi2p[12], I3,   a2);
  h1 = dot2(wh1p[0],  O0.x, h1);  h2 = dot2(wh2p[0],  O0.x, h2);
  h1 = dot2(wh1p[1],  O0.y, h1);  h2 = dot2(wh2p[1],  O0.y, h2);
  h1 = dot2(wh1p[2],  O0.z, h1);  h2 = dot2(wh2p[2],  O0.z, h2);
  h1 = dot2(wh1p[3],  O0.w, h1);  h2 = dot2(wh2p[3],  O0.w, h2);
  h1 = dot2(wh1p[4],  O1.x, h1);  h2 = dot2(wh2p[4],  O1.x, h2);
  h1 = dot2(wh1p[5],  O1.y, h1);  h2 = dot2(wh2p[5],  O1.y, h2);
  h1 = dot2(wh1p[6],  O1.z, h1);  h2 = dot2(wh2p[6],  O1.z, h2);
  h1 = dot2(wh1p[7],  O1.w, h1);  h2 = dot2(wh2p[7],  O1.w, h2);
  h1 = dot2(wh1p[8],  O2.x, h1);  h2 = dot2(wh2p[8],  O2.x, h2);
  h1 = dot2(wh1p[9],  O2.y, h1);  h2 = dot2(wh2p[9],  O2.y, h2);
  h1 = dot2(wh1p[10], O2.z, h1);  h2 = dot2(wh2p[10], O2.z, h2);
  h1 = dot2(wh1p[11], O2.w, h1);  h2 = dot2(wh2p[11], O2.w, h2);
  h1 = dot2(wh1p[12], O3,   h1);  h2 = dot2(wh2p[12], O3,   h2);

  const float p1 = a1 + h1;
  const float p2 = a2 + h2;
  const float G1 = sigm(p1);                    // i (g=0) / f (g=1)
  const float G2 = s2 * sigm(s2 * p2) - s2m1;   // tanh g / sigm o

  const float q1 = __shfl_xor(G1, 1);           // partner's pair
  const float q2 = __shfl_xor(G2, 1);

  if (g == 0) {                                 // q1=f, q2=o
    c = q1 * c + G1 * G2;                       // f*c + i*g
    const float th = 2.0f * sigm(2.0f * c) - 1.0f;
    const float h = q2 * th;                    // o * tanh(c)
    const float hp = __shfl_xor(h, 2);          // partner owner's h
    if ((lane & 3) == 0) {                      // even-u owners publish
      dst[lane >> 2] = pkh2(h, (u == 24) ? 0.f : hp);
    }
  }
}

// R10: two batch elems per block (256 blocks = 1/CU, no sequential rounds)
// + chunk-ahead x prefetch. R9 post-mortem: VALUBusy 63%, occupancy stuck
// at 11 waves/CU (1 block resident; 512 blocks ran as 2 rounds) ->
// latency-bound with ~2.75 waves/SIMD. Fix: (a) E=2 elems/block doubles
// independent work per wave (8 dot chains), halves barriers/work, kills
// round 2; (b) wave-0 preloads a FULL x-chunk into regs one step ahead
// (~step-length cover vs ~300cy before, HBM lat ~900cy). Per-elem math
// bit-identical to R9. 12 waves: 0..9 layers (both elems), 10/11 = FC
// for elem 0/1.
__launch_bounds__(768)
__global__ void lstm_fused(const float* __restrict__ x,
                           const float* __restrict__ h0,
                           const float* __restrict__ c0,
                           const float* __restrict__ Wih,
                           const float* __restrict__ Whh,
                           const float* __restrict__ bias,
                           const float* __restrict__ fcw,
                           const float* __restrict__ fcb,
                           float* __restrict__ out) {
  // hs[parity][slot][cell][elem][dword]: 13 f16x2 dwords used, stride 16
  __shared__ __align__(16) unsigned hs[2][LAYERS + 1][CH][2][16];
  __shared__ float eb[2][CH][8];   // FC softmax exp staging

  const int tid = threadIdx.x;
  const int w = tid >> 6;          // 0..9 layers, 10/11 = FC elem 0/1
  const int lane = tid & 63;
  const int b0 = blockIdx.x * 2;   // first batch elem of this block
  const int g = lane & 1;
  const int u = lane >> 1;
  const bool on = (w < LAYERS) && (lane < 50);
  const bool isfc = (w >= LAYERS) && (lane < 7 * CH);
  const int efc = w - LAYERS;              // FC: which elem
  const int jg = lane / 7;                 // FC: cell within chunk
  const int cls = lane - jg * 7;           // FC: class

  unsigned wi1p[13], wi2p[13], wh1p[13], wh2p[13];  // f16-pair weights
  float b1 = 0.f, b2 = 0.f, cA = 0.f, cB = 0.f;
  float xA[CH], xB[CH];            // wave-0 staged x chunk (one ahead)
#pragma unroll
  for (int j = 0; j < CH; ++j) { xA[j] = 0.f; xB[j] = 0.f; }

  if (on) {
    const int r1 = g ? (u + 25) : u;        // f_u : i_u
    const int r2 = g ? (u + 75) : (u + 50); // o_u : g_u
    const float* pi1 = Wih + (w * 100 + r1) * 25;
    const float* pi2 = Wih + (w * 100 + r2) * 25;
    const float* ph1 = Whh + (w * 100 + r1) * 25;
    const float* ph2 = Whh + (w * 100 + r2) * 25;
#pragma unroll
    for (int j = 0; j < 13; ++j) {
      const int k0 = 2 * j, k1 = 2 * j + 1;
      const float e1 = (k1 < 25) ? pi1[k1] : 0.f;
      const float e2 = (k1 < 25) ? pi2[k1] : 0.f;
      const float e3 = (k1 < 25) ? ph1[k1] : 0.f;
      const float e4 = (k1 < 25) ? ph2[k1] : 0.f;
      wi1p[j] = pkh2(pi1[k0], e1);
      wi2p[j] = pkh2(pi2[k0], e2);
      wh1p[j] = pkh2(ph1[k0], e3);
      wh2p[j] = pkh2(ph2[k0], e4);
    }
    b1 = bias[w * 100 + r1];
    b2 = bias[w * 100 + r2];
    if (g == 0) {
      cA = c0[(w * BQ + b0) * 25 + u];
      cB = c0[(w * BQ + b0 + 1) * 25 + u];
    }
  } else if (isfc) {
    const float* pf = fcw + cls * 25;
#pragma unroll
    for (int j = 0; j < 13; ++j) {
      const int k0 = 2 * j, k1 = 2 * j + 1;
      wh1p[j] = pkh2(pf[k0], (k1 < 25) ? pf[k1] : 0.f);
    }
    b1 = fcb[cls];
  }

  // h0 -> packed pairs at [prev-parity of first active step][w+1][CH-1][e]
#pragma unroll
  for (int e = 0; e < 2; ++e) {
    float h00 = 0.f;
    if (on && g == 0) h00 = h0[(w * BQ + b0 + e) * 25 + u];
    const float hp = __shfl_xor(h00, 2);       // partner owner (u^1)
    if (on && (lane & 3) == 0) {
      hs[(w & 1) ^ 1][w + 1][CH - 1][e][lane >> 2] =
          pkh2(h00, (u == 24) ? 0.f : hp);
    }
  }

  // Wave-0 x staging lanes: lane<26, se = elem (0/1), li = dword 0..12
  const int se = (lane >= 13) ? 1 : 0;
  const int li = lane - 13 * se;
  const int i0 = 2 * li;
  const int i1 = (li < 12) ? (2 * li + 1) : 0;   // clamped (in-bounds)
  const bool stager = (w == 0) && (lane < 26);

  if (stager) {
    // chunk 0 -> parity 1 (read at m=0)
#pragma unroll
    for (int j = 0; j < CH; ++j) {
      const float* p = x + ((size_t)j * BQ + (b0 + se)) * 25;
      const float va = p[i0];
      const float vb = (li < 12) ? p[i1] : 0.f;
      hs[1][0][j][se][li] = pkh2(va, vb);
    }
    // preload chunk 1 into regs (staged to LDS at m=0)
#pragma unroll
    for (int j = 0; j < CH; ++j) {
      const float* p = x + ((size_t)(CH + j) * BQ + (b0 + se)) * 25;
      xA[j] = p[i0];
      xB[j] = (li < 12) ? p[i1] : 0.f;
    }
  }
  __syncthreads();

  const float s2 = g ? 1.0f : 2.0f;            // gate2: tanh (g) vs sigm (o)
  const float s2m1 = s2 - 1.0f;

  for (int m = 0; m < NCH + LAYERS; ++m) {
    const int pr = (m & 1) ^ 1;                // read parity
    const int pw = m & 1;                      // write parity

    if (w < LAYERS) {
      if (stager) {
        // stage chunk m+1 from regs into pw buffer (read next step)
        if (m + 1 < NCH) {
#pragma unroll
          for (int j = 0; j < CH; ++j) {
            hs[pw][0][j][se][li] = pkh2(xA[j], xB[j]);
          }
        }
        // issue loads for chunk m+2 (full step of latency cover)
        if (m + 2 < NCH) {
          const size_t tbase = (size_t)(m + 2) * CH;
#pragma unroll
          for (int j = 0; j < CH; ++j) {
            const float* p = x + ((tbase + j) * BQ + (b0 + se)) * 25;
            xA[j] = p[i0];
            xB[j] = (li < 12) ? p[i1] : 0.f;
          }
        }
      }
      const int mc = m - w;                    // chunk index (wave-uniform)
      if ((unsigned)mc < (unsigned)NCH && lane < 50) {
        const unsigned* ibase = &hs[pr][w][0][0][0];      // input chunk
        const unsigned* o0b = &hs[pr][w + 1][CH - 1][0][0]; // h(mc*CH-1)
        unsigned* obase = &hs[pw][w + 1][0][0][0];        // publish chunk

#pragma unroll
        for (int j = 0; j < CH; ++j) {
          const unsigned* ip0 = ibase + j * 32;
          const unsigned* ip1 = ip0 + 16;
          const unsigned* op0 = (j == 0) ? o0b : (obase + (j - 1) * 32);
          const unsigned* op1 = op0 + 16;
          unsigned* d0 = obase + j * 32;
          unsigned* d1 = d0 + 16;
          lstm_cell(ip0, op0, wi1p, wi2p, wh1p, wh2p, b1, b2, s2, s2m1,
                    g, u, lane, cA, d0);
          lstm_cell(ip1, op1, wi1p, wi2p, wh1p, wh2p, b1, b2, s2, s2m1,
                    g, u, lane, cB, d1);
        }
      }
    } else if (isfc) {
      // FC + softmax for elem efc: chunk mc = m-10 (parity pr)
      const int mc = m - LAYERS;
      if ((unsigned)mc < (unsigned)NCH) {
        const unsigned* hp = &hs[pr][LAYERS][jg][efc][0];
        const uint4 H0 = *(const uint4*)(hp + 0);
        const uint4 H1 = *(const uint4*)(hp + 4);
        const uint4 H2 = *(const uint4*)(hp + 8);
        const unsigned H3 = hp[12];
        float acc = b1;
        acc = dot2(wh1p[0],  H0.x, acc);
        acc = dot2(wh1p[1],  H0.y, acc);
        acc = dot2(wh1p[2],  H0.z, acc);
        acc = dot2(wh1p[3],  H0.w, acc);
        acc = dot2(wh1p[4],  H1.x, acc);
        acc = dot2(wh1p[5],  H1.y, acc);
        acc = dot2(wh1p[6],  H1.z, acc);
        acc = dot2(wh1p[7],  H1.w, acc);
        acc = dot2(wh1p[8],  H2.x, acc);
        acc = dot2(wh1p[9],  H2.y, acc);
        acc = dot2(wh1p[10], H2.z, acc);
        acc = dot2(wh1p[11], H2.w, acc);
        acc = dot2(wh1p[12], H3,   acc);
        const float e = __expf(acc);            // logits small; no max-sub
        eb[efc][jg][cls] = e;                   // same-wave LDS, ordered
        const float ssum = eb[efc][jg][0] + eb[efc][jg][1] + eb[efc][jg][2] +
                           eb[efc][jg][3] + eb[efc][jg][4] + eb[efc][jg][5] +
                           eb[efc][jg][6];
        const int t = mc * CH + jg;
        out[((size_t)t * BQ + (b0 + efc)) * NC + cls] =
            e * __builtin_amdgcn_rcpf(ssum);
      }
    }
    __syncthreads();   // ONE barrier per chunk-step (266 total)
  }
}

extern "C" void kernel_launch(void* const* d_in, const int* in_sizes, int n_in,
                              void* d_out, int out_size, void* d_ws, size_t ws_size,
                              hipStream_t stream) {
  const float* x   = (const float*)d_in[0];
  const float* h0  = (const float*)d_in[1];
  const float* c0  = (const float*)d_in[2];
  const float* Wih = (const float*)d_in[3];
  const float* Whh = (const float*)d_in[4];
  const float* b   = (const float*)d_in[5];
  const float* fcw = (const float*)d_in[6];
  const float* fcb = (const float*)d_in[7];
  float* out = (float*)d_out;

  lstm_fused<<<dim3(256), dim3(768), 0, stream>>>(x, h0, c0, Wih, Whh, b, fcw,
                                                  fcb, out);
}

// Round 3
// 1983.341 us; speedup vs baseline: 1.4939x; 1.2120x over previous
//
#include <hip/hip_runtime.h>

#define TT 2048
#define BQ 512
#define LAYERS 10
#define NC 7
#define CH 8               // timesteps per chunk (per barrier interval)
#define NCH (TT / CH)      // 256 chunks

// LDS layout strides (in dwords). Elem slot padded 13->20 so the FC
// chunk-read (stride C_S=40 dwords) lands on banks {0,8,16,24} -> 2-way
// (free) instead of the 8-way conflict of stride 32. All strides are
// 16B multiples so uint4 reads stay aligned.
#define E_S 20
#define C_S (2 * E_S)              // 40
#define S_S (CH * C_S)             // 320
#define P_S ((LAYERS + 1) * S_S)   // 3520

typedef _Float16 half2v __attribute__((ext_vector_type(2)));

__device__ __forceinline__ float sigm(float z) {
  return __builtin_amdgcn_rcpf(1.0f + __expf(-z));
}
// f32 += dot(f16x2, f16x2) -- v_dot2_f32_f16
__device__ __forceinline__ float dot2(unsigned w, unsigned v, float acc) {
  return __builtin_amdgcn_fdot2(__builtin_bit_cast(half2v, w),
                                __builtin_bit_cast(half2v, v), acc, false);
}
// RNE pack of two floats into f16x2 dword
__device__ __forceinline__ unsigned pkh2(float a, float b) {
  union { _Float16 h[2]; unsigned u; } z;
  z.h[0] = (_Float16)a; z.h[1] = (_Float16)b;
  return z.u;
}

// R11: unit-per-lane gate layout. R10 post-mortem: VALUBusy 65%, per-wave
// issue duty ~25% -- stalls dominated by LDS round-trips (16 ds_reads +
// 4 shfl per cell-pair on the LDS pipe) and the half-masked g-split tail.
// New mapping: lane = 2u+e owns ALL 4 gate rows (i,f,g,o) of unit u,
// elem e; both elems computed simultaneously across the 50 lanes.
//  - LDS reads halve (lane reads only its elem's I/O slots)
//  - shfl 4 -> 1 per cell (only the h-pair exchange, xor 2 = same-elem
//    neighbor unit)
//  - no divergent c-update tail; activations all in-lane, full width
//  - 8 independent dot chains/cell (ILP)
//  - elem-padded LDS strides kill the FC bank conflict
// Per-row arithmetic bit-identical to R10 (same chains, same exprs).
// 12 waves: 0..9 layers, 10/11 = FC elem 0/1. Wave-0 lanes 0..51 stage x
// (4 lanes-groups of 13: elem = grp&1, cells (grp>>1)*4..+3).
__launch_bounds__(768, 3)
__global__ void lstm_fused(const float* __restrict__ x,
                           const float* __restrict__ h0,
                           const float* __restrict__ c0,
                           const float* __restrict__ Wih,
                           const float* __restrict__ Whh,
                           const float* __restrict__ bias,
                           const float* __restrict__ fcw,
                           const float* __restrict__ fcb,
                           float* __restrict__ out) {
  __shared__ __align__(16) unsigned hs[2 * P_S];
  __shared__ float eb[2][CH][8];   // FC softmax exp staging

  const int tid = threadIdx.x;
  const int w = tid >> 6;          // 0..9 layers, 10/11 = FC elem 0/1
  const int lane = tid & 63;
  const int b0 = blockIdx.x * 2;   // first batch elem of this block
  const int e = lane & 1;          // element
  const int u = lane >> 1;         // unit 0..24
  const bool on = (w < LAYERS) && (lane < 50);
  const bool isfc = (w >= LAYERS) && (lane < 7 * CH);
  const int efc = w - LAYERS;              // FC: which elem
  const int jg = lane / 7;                 // FC: cell within chunk
  const int cls = lane - jg * 7;           // FC: class

  // Weights: Wx/Wh[r][k] = f16-pair k of gate-row r (i,f,g,o) for unit u.
  // FC waves reuse Wx[0][*] and bb[0] for fc weights/bias.
  unsigned Wx[4][13], Wh[4][13];
  float bb[4] = {0.f, 0.f, 0.f, 0.f};
  float c = 0.f;

  // Wave-0 x staging roles: 52 lanes = 4 groups of 13.
  const int sg = lane / 13;                // group 0..3
  const int li = lane - sg * 13;           // dword 0..12
  const int se = sg & 1;                   // staged elem
  const int jb = (sg >> 1) * 4;            // first cell of this group
  const int i0 = 2 * li;
  const int i1 = (li < 12) ? (2 * li + 1) : 0;   // clamped in-bounds
  const bool stager = (w == 0) && (lane < 52);
  float xA[4], xB[4];
#pragma unroll
  for (int jj = 0; jj < 4; ++jj) { xA[jj] = 0.f; xB[jj] = 0.f; }

  if (on) {
#pragma unroll
    for (int r = 0; r < 4; ++r) {
      const int row = u + 25 * r;          // torch order: i,f,g,o
      const float* px = Wih + (w * 100 + row) * 25;
      const float* ph = Whh + (w * 100 + row) * 25;
#pragma unroll
      for (int k = 0; k < 13; ++k) {
        const int k0 = 2 * k, k1 = 2 * k + 1;
        Wx[r][k] = pkh2(px[k0], (k1 < 25) ? px[k1] : 0.f);
        Wh[r][k] = pkh2(ph[k0], (k1 < 25) ? ph[k1] : 0.f);
      }
      bb[r] = bias[w * 100 + row];
    }
    c = c0[(w * BQ + b0 + e) * 25 + u];
  } else if (isfc) {
    const float* pf = fcw + cls * 25;
#pragma unroll
    for (int k = 0; k < 13; ++k) {
      const int k0 = 2 * k, k1 = 2 * k + 1;
      Wx[0][k] = pkh2(pf[k0], (k1 < 25) ? pf[k1] : 0.f);
    }
    bb[0] = fcb[cls];
  }

  // h0 -> packed pairs at [prev-parity of first active step][w+1][CH-1][e].
  {
    float h00 = 0.f;
    if (on) h00 = h0[(w * BQ + b0 + e) * 25 + u];
    const float hn = __shfl_xor(h00, 2);   // same-elem neighbor unit u^1
    if (on && (lane & 2) == 0) {           // even-u owners publish pairs
      hs[((w & 1) ^ 1) * P_S + (w + 1) * S_S + (CH - 1) * C_S + e * E_S +
         (u >> 1)] = pkh2(h00, (u == 24) ? 0.f : hn);
    }
  }

  if (stager) {
    // chunk 0 -> parity 1 (read at m=0)
#pragma unroll
    for (int jj = 0; jj < 4; ++jj) {
      const float* p = x + ((size_t)(jb + jj) * BQ + (b0 + se)) * 25;
      hs[1 * P_S + (jb + jj) * C_S + se * E_S + li] =
          pkh2(p[i0], (li < 12) ? p[i1] : 0.f);
    }
    // preload chunk 1 into regs (staged to LDS at m=0)
#pragma unroll
    for (int jj = 0; jj < 4; ++jj) {
      const float* p = x + ((size_t)(CH + jb + jj) * BQ + (b0 + se)) * 25;
      xA[jj] = p[i0];
      xB[jj] = (li < 12) ? p[i1] : 0.f;
    }
  }
  __syncthreads();

  for (int m = 0; m < NCH + LAYERS; ++m) {
    const int pr = (m & 1) ^ 1;                // read parity
    const int pw = m & 1;                      // write parity

    if (w < LAYERS) {
      if (stager) {
        // stage chunk m+1 from regs into pw buffer (read next step)
        if (m + 1 < NCH) {
#pragma unroll
          for (int jj = 0; jj < 4; ++jj) {
            hs[pw * P_S + (jb + jj) * C_S + se * E_S + li] =
                pkh2(xA[jj], xB[jj]);
          }
        }
        // issue loads for chunk m+2 (full step of latency cover)
        if (m + 2 < NCH) {
          const size_t tb = (size_t)(m + 2) * CH + jb;
#pragma unroll
          for (int jj = 0; jj < 4; ++jj) {
            const float* p = x + ((tb + jj) * BQ + (b0 + se)) * 25;
            xA[jj] = p[i0];
            xB[jj] = (li < 12) ? p[i1] : 0.f;
          }
        }
      }
      const int mc = m - w;                    // chunk index (wave-uniform)
      if ((unsigned)mc < (unsigned)NCH && lane < 50) {
        const unsigned* ibase = hs + pr * P_S + w * S_S + e * E_S;
        const unsigned* o0p =
            hs + pr * P_S + (w + 1) * S_S + (CH - 1) * C_S + e * E_S;
        unsigned* obase = hs + pw * P_S + (w + 1) * S_S + e * E_S;

#pragma unroll
        for (int j = 0; j < CH; ++j) {
          const unsigned* ip = ibase + j * C_S;
          const unsigned* op = (j == 0) ? o0p : (obase + (j - 1) * C_S);
          unsigned* dst = obase + j * C_S;

          unsigned Iv[13], Ov[13];
          *(uint4*)&Iv[0] = *(const uint4*)(ip + 0);
          *(uint4*)&Iv[4] = *(const uint4*)(ip + 4);
          *(uint4*)&Iv[8] = *(const uint4*)(ip + 8);
          Iv[12] = ip[12];
          *(uint4*)&Ov[0] = *(const uint4*)(op + 0);
          *(uint4*)&Ov[4] = *(const uint4*)(op + 4);
          *(uint4*)&Ov[8] = *(const uint4*)(op + 8);
          Ov[12] = op[12];

          float ai = bb[0], af = bb[1], ag = bb[2], ao = bb[3];
          float hi = 0.f, hf = 0.f, hg = 0.f, ho = 0.f;
#pragma unroll
          for (int k = 0; k < 13; ++k) {
            ai = dot2(Wx[0][k], Iv[k], ai);
            af = dot2(Wx[1][k], Iv[k], af);
            ag = dot2(Wx[2][k], Iv[k], ag);
            ao = dot2(Wx[3][k], Iv[k], ao);
            hi = dot2(Wh[0][k], Ov[k], hi);
            hf = dot2(Wh[1][k], Ov[k], hf);
            hg = dot2(Wh[2][k], Ov[k], hg);
            ho = dot2(Wh[3][k], Ov[k], ho);
          }
          const float gi = sigm(ai + hi);
          const float gf = sigm(af + hf);
          const float pg = ag + hg;
          const float gg = 2.0f * sigm(2.0f * pg) - 1.0f;  // tanh
          const float go = sigm(ao + ho);
          c = gf * c + gi * gg;
          const float th = 2.0f * sigm(2.0f * c) - 1.0f;   // tanh(c)
          const float hv = go * th;
          const float hn = __shfl_xor(hv, 2);  // same-elem neighbor unit
          if ((lane & 2) == 0) {               // even-u owners publish
            dst[u >> 1] = pkh2(hv, (u == 24) ? 0.f : hn);
          }
        }
      }
    } else if (isfc) {
      // FC + softmax for elem efc: chunk mc = m-10 (parity pr)
      const int mc = m - LAYERS;
      if ((unsigned)mc < (unsigned)NCH) {
        const unsigned* hp =
            hs + pr * P_S + LAYERS * S_S + jg * C_S + efc * E_S;
        unsigned Hv[13];
        *(uint4*)&Hv[0] = *(const uint4*)(hp + 0);
        *(uint4*)&Hv[4] = *(const uint4*)(hp + 4);
        *(uint4*)&Hv[8] = *(const uint4*)(hp + 8);
        Hv[12] = hp[12];
        float acc = bb[0];
#pragma unroll
        for (int k = 0; k < 13; ++k) acc = dot2(Wx[0][k], Hv[k], acc);
        const float ev = __expf(acc);           // logits small; no max-sub
        eb[efc][jg][cls] = ev;                  // same-wave LDS, ordered
        const float ssum = eb[efc][jg][0] + eb[efc][jg][1] + eb[efc][jg][2] +
                           eb[efc][jg][3] + eb[efc][jg][4] + eb[efc][jg][5] +
                           eb[efc][jg][6];
        const int t = mc * CH + jg;
        out[((size_t)t * BQ + (b0 + efc)) * NC + cls] =
            ev * __builtin_amdgcn_rcpf(ssum);
      }
    }
    __syncthreads();   // ONE barrier per chunk-step (266 total)
  }
}

extern "C" void kernel_launch(void* const* d_in, const int* in_sizes, int n_in,
                              void* d_out, int out_size, void* d_ws, size_t ws_size,
                              hipStream_t stream) {
  const float* x   = (const float*)d_in[0];
  const float* h0  = (const float*)d_in[1];
  const float* c0  = (const float*)d_in[2];
  const float* Wih = (const float*)d_in[3];
  const float* Whh = (const float*)d_in[4];
  const float* b   = (const float*)d_in[5];
  const float* fcw = (const float*)d_in[6];
  const float* fcb = (const float*)d_in[7];
  float* out = (float*)d_out;

  lstm_fused<<<dim3(256), dim3(768), 0, stream>>>(x, h0, c0, Wih, Whh, b, fcw,
                                                  fcb, out);
}